// Round 5
// baseline (12730.732 us; speedup 1.0000x reference)
//
#include <hip/hip_runtime.h>

// LSTM T=16384, B=32, H=96. One block per batch (32 blocks × 768 threads).
// R1-R4 lesson: compiler refuses to keep ~50 fp32 weights/thread resident ->
// use f16 weights via v_dot2_f32_f16: 24 VGPRs of weights/thread, fp32 acc.
// Thread (j = tid>>3, s = tid&7) computes ALL 4 gates of cell j over k-slice
// [12s,12s+12); ds_swizzle butterfly over the 8 slice lanes; lane s==0 does
// the c/h update in registers. ONE barrier per step; no act_s roundtrip.
// h history kept as f16 in a 512-step rolling LDS buffer; fc projection done
// in bulk every 512 steps (amortized), so the steady-state step has no global
// memory ops and no output reduce on the critical path.

constexpr int HH  = 96;
constexpr int BB  = 32;
constexpr int TT  = 16384;
constexpr int TH  = 768;    // 12 waves
constexpr int NS  = 512;    // h history window
constexpr int ROWP = 100;   // halves per hist row (96 padded -> breaks flush bank conflicts)
constexpr int CH  = 2048;   // x chunk in LDS

typedef _Float16 f16x2 __attribute__((ext_vector_type(2)));

#if defined(__has_builtin)
#if __has_builtin(__builtin_amdgcn_fdot2)
#define FDOT2(a, b, c) __builtin_amdgcn_fdot2((a), (b), (c), false)
#endif
#endif
#ifndef FDOT2
#define FDOT2(a, b, c) fmaf((float)(a).x, (float)(b).x, \
                            fmaf((float)(a).y, (float)(b).y, (c)))
#endif

template <int PAT>
__device__ __forceinline__ float swz_add(float v) {
    int r = __builtin_amdgcn_ds_swizzle(__builtin_bit_cast(int, v), PAT);
    return v + __builtin_bit_cast(float, r);
}

__device__ __forceinline__ float sigm(float v) {
    return __builtin_amdgcn_rcpf(1.0f + __expf(-v));
}
__device__ __forceinline__ float tanh_f(float v) {
    return fmaf(2.0f, __builtin_amdgcn_rcpf(1.0f + __expf(-2.0f * v)), -1.0f);
}

__attribute__((amdgpu_flat_work_group_size(TH, TH), amdgpu_waves_per_eu(3, 3)))
__global__ void lstm_kernel(const float* __restrict__ x,
                            const float* __restrict__ w_ih,
                            const float* __restrict__ w_hh,
                            const float* __restrict__ b_ih,
                            const float* __restrict__ b_hh,
                            const float* __restrict__ fc_w,
                            const float* __restrict__ fc_b,
                            float* __restrict__ out) {
    __shared__ _Float16 hist[NS * ROWP];  // 100 KB rolling h history (f16)
    __shared__ float xs[CH];              // 8 KB x chunk
    __shared__ float fcw_s[HH];

    const int tid  = threadIdx.x;
    const int b    = blockIdx.x;
    const int j    = tid >> 3;   // cell 0..95
    const int s    = tid & 7;    // k-slice: k in [12s, 12s+12)
    const bool lead = (s == 0);

    // ---- one-time: pack w_hh[(g*96+j)][12s..12s+12) as 24 f16x2 VGPRs ----
    f16x2 W[4][6];
#pragma unroll
    for (int g = 0; g < 4; ++g) {
        const float* wr = w_hh + (g * HH + j) * HH + 12 * s;
#pragma unroll
        for (int m = 0; m < 6; ++m)
            W[g][m] = f16x2{(_Float16)wr[2 * m], (_Float16)wr[2 * m + 1]};
    }
#pragma unroll
    for (int g = 0; g < 4; ++g)
#pragma unroll
        for (int m = 0; m < 6; ++m) asm volatile("" : "+v"(W[g][m]));

    float wih[4], bias[4];
#pragma unroll
    for (int g = 0; g < 4; ++g) {
        wih[g]  = w_ih[g * HH + j];
        bias[g] = b_ih[g * HH + j] + b_hh[g * HH + j];
    }
    const float fcb = fc_b[0];
    float c = 0.0f;

    for (int i = tid; i < HH; i += TH) {
        fcw_s[i] = fc_w[i];
        hist[(NS - 1) * ROWP + i] = (_Float16)0.0f;  // h(-1) = 0
    }

    // Bulk fc projection for steps [t0, t0+NS): out = hist.fcw + fcb + x
    auto flush = [&](int t0) {
        if (tid < NS) {
            const uint2* hr = (const uint2*)(hist + tid * ROWP);
            float a = 0.0f;
#pragma unroll
            for (int m = 0; m < 24; ++m) {
                uint2 u = hr[m];
                f16x2 p0 = __builtin_bit_cast(f16x2, u.x);
                f16x2 p1 = __builtin_bit_cast(f16x2, u.y);
                a = fmaf((float)p0.x, fcw_s[4 * m + 0], a);
                a = fmaf((float)p0.y, fcw_s[4 * m + 1], a);
                a = fmaf((float)p1.x, fcw_s[4 * m + 2], a);
                a = fmaf((float)p1.y, fcw_s[4 * m + 3], a);
            }
            out[(t0 + tid) * BB + b] = a + fcb + xs[(t0 + tid) & (CH - 1)];
        }
    };

    for (int t = 0; t < TT; ++t) {
        if (t > 0 && (t & (NS - 1)) == 0) {   // flush BEFORE any xs refill
            flush(t - NS);
            __syncthreads();
        }
        if ((t & (CH - 1)) == 0) {            // covers t=0 (also init barrier)
            for (int i = tid; i < CH; i += TH) xs[i] = x[(t + i) * BB + b];
            __syncthreads();
        }

        // ---- gate dots: 4 gates x 6 fdot2 over h(t-1) slice ----
        const int pr = (t - 1) & (NS - 1);    // t=0 -> 511 (zeros)
        const uint2* hrow = (const uint2*)((const uint32_t*)(hist + pr * ROWP) + 6 * s);
        uint2 ua = hrow[0], ub = hrow[1], uc = hrow[2];
        f16x2 h2[6] = {__builtin_bit_cast(f16x2, ua.x), __builtin_bit_cast(f16x2, ua.y),
                       __builtin_bit_cast(f16x2, ub.x), __builtin_bit_cast(f16x2, ub.y),
                       __builtin_bit_cast(f16x2, uc.x), __builtin_bit_cast(f16x2, uc.y)};
        const float xv = xs[t & (CH - 1)];

        float acc[4];
#pragma unroll
        for (int g = 0; g < 4; ++g) {
            acc[g] = lead ? fmaf(xv, wih[g], bias[g]) : 0.0f;
#pragma unroll
            for (int m = 0; m < 6; ++m) acc[g] = FDOT2(W[g][m], h2[m], acc[g]);
        }

        // ---- butterfly reduce over the 8 slice lanes (xor 1,2,4) ----
#pragma unroll
        for (int g = 0; g < 4; ++g) {
            acc[g] = swz_add<0x041F>(acc[g]);
            acc[g] = swz_add<0x081F>(acc[g]);
            acc[g] = swz_add<0x101F>(acc[g]);
        }

        // ---- c/h update in-register on the lead lane; write h(t) ----
        if (lead) {
            const float iv = sigm(acc[0]);
            const float fv = sigm(acc[1]);
            const float gv = tanh_f(acc[2]);
            const float ov = sigm(acc[3]);
            c = fmaf(fv, c, iv * gv);
            const float h = ov * tanh_f(c);
            hist[(t & (NS - 1)) * ROWP + j] = (_Float16)h;
        }
        __syncthreads();   // h(t) visible; hist row t&511 overwrite safe
    }
    flush(TT - NS);        // last window (loop ended with a barrier)
}

extern "C" void kernel_launch(void* const* d_in, const int* in_sizes, int n_in,
                              void* d_out, int out_size, void* d_ws, size_t ws_size,
                              hipStream_t stream) {
    const float* x    = (const float*)d_in[0];
    const float* w_ih = (const float*)d_in[1];
    const float* w_hh = (const float*)d_in[2];
    const float* b_ih = (const float*)d_in[3];
    const float* b_hh = (const float*)d_in[4];
    const float* fc_w = (const float*)d_in[5];
    const float* fc_b = (const float*)d_in[6];
    float* out = (float*)d_out;

    lstm_kernel<<<dim3(BB), dim3(TH), 0, stream>>>(x, w_ih, w_hh, b_ih, b_hh,
                                                   fc_w, fc_b, out);
}

// Round 6
// 9771.652 us; speedup vs baseline: 1.3028x; 1.3028x over previous
//
#include <hip/hip_runtime.h>

// LSTM T=16384, B=32, H=96. One block per batch (32 blocks x 768 threads).
// R3-R5 post-mortem: all landed ~1860 cyc/step because the per-CU LDS pipe was
// saturated (R3/R4: 147KB/step h reads; R5: 144 ds_swizzle/step). This round
// the 8-lane slice reduction uses VALU DPP adds (quad_perm xor1/xor2 +
// row_half_mirror) -> DS traffic/step is only the h-row reads (~18KB) + 1 b16
// write. Thread (j=tid>>3, s=tid&7) computes all 4 gates of cell j over
// k-slice [12s,12s+12) with v_dot2_f32_f16 (f16 weights, fp32 acc, 24 VGPRs
// of weights). Lane s==0 does c/h update in-register. One barrier per step.
// h history (f16) in a 512-step rolling LDS buffer; fc projection bulk-flushed
// every 512 steps (amortized ~2 cyc/step).

constexpr int HH  = 96;
constexpr int BB  = 32;
constexpr int TT  = 16384;
constexpr int TH  = 768;    // 12 waves
constexpr int NS  = 512;    // h history window
constexpr int ROWP = 100;   // halves per hist row (padded)
constexpr int CH  = 2048;   // x chunk in LDS

typedef _Float16 f16x2 __attribute__((ext_vector_type(2)));

#if defined(__has_builtin)
#if __has_builtin(__builtin_amdgcn_fdot2)
#define FDOT2(a, b, c) __builtin_amdgcn_fdot2((a), (b), (c), false)
#endif
#endif
#ifndef FDOT2
#define FDOT2(a, b, c) fmaf((float)(a).x, (float)(b).x, \
                            fmaf((float)(a).y, (float)(b).y, (c)))
#endif

// VALU cross-lane add via DPP16 (no DS pipe). bound_ctrl=1 -> invalid lanes
// read 0 (additive identity); all lanes are active here anyway.
template <int CTRL>
__device__ __forceinline__ float dpp_add(float v) {
    int r = __builtin_amdgcn_update_dpp(0, __builtin_bit_cast(int, v),
                                        CTRL, 0xF, 0xF, true);
    return v + __builtin_bit_cast(float, r);
}
constexpr int DPP_XOR1 = 0xB1;  // quad_perm [1,0,3,2]
constexpr int DPP_XOR2 = 0x4E;  // quad_perm [2,3,0,1]
constexpr int DPP_HMIR = 0x141; // row_half_mirror: lane i <-> 7-i in each 8

__device__ __forceinline__ float sigm(float v) {
    return __builtin_amdgcn_rcpf(1.0f + __expf(-v));
}
__device__ __forceinline__ float tanh_f(float v) {
    return fmaf(2.0f, __builtin_amdgcn_rcpf(1.0f + __expf(-2.0f * v)), -1.0f);
}

__attribute__((amdgpu_flat_work_group_size(TH, TH), amdgpu_waves_per_eu(3, 3)))
__global__ void lstm_kernel(const float* __restrict__ x,
                            const float* __restrict__ w_ih,
                            const float* __restrict__ w_hh,
                            const float* __restrict__ b_ih,
                            const float* __restrict__ b_hh,
                            const float* __restrict__ fc_w,
                            const float* __restrict__ fc_b,
                            float* __restrict__ out) {
    __shared__ _Float16 hist[NS * ROWP];  // 100 KB rolling h history (f16)
    __shared__ float xs[CH];              // 8 KB x chunk
    __shared__ float fcw_s[HH];

    const int tid  = threadIdx.x;
    const int b    = blockIdx.x;
    const int j    = tid >> 3;   // cell 0..95
    const int s    = tid & 7;    // k-slice: k in [12s, 12s+12)
    const bool lead = (s == 0);

    // ---- one-time: pack w_hh[(g*96+j)][12s..12s+12) as 24 f16x2 VGPRs ----
    f16x2 W[4][6];
#pragma unroll
    for (int g = 0; g < 4; ++g) {
        const float* wr = w_hh + (g * HH + j) * HH + 12 * s;
#pragma unroll
        for (int m = 0; m < 6; ++m)
            W[g][m] = f16x2{(_Float16)wr[2 * m], (_Float16)wr[2 * m + 1]};
    }
#pragma unroll
    for (int g = 0; g < 4; ++g)
#pragma unroll
        for (int m = 0; m < 6; ++m) asm volatile("" : "+v"(W[g][m]));

    float wih[4], bias[4];
#pragma unroll
    for (int g = 0; g < 4; ++g) {
        wih[g]  = w_ih[g * HH + j];
        bias[g] = b_ih[g * HH + j] + b_hh[g * HH + j];
    }
    const float fcb = fc_b[0];
    float c = 0.0f;

    for (int i = tid; i < HH; i += TH) {
        fcw_s[i] = fc_w[i];
        hist[(NS - 1) * ROWP + i] = (_Float16)0.0f;  // h(-1) = 0
    }

    // Bulk fc projection for steps [t0, t0+NS): out = hist.fcw + fcb + x
    auto flush = [&](int t0) {
        if (tid < NS) {
            const uint2* hr = (const uint2*)(hist + tid * ROWP);
            float a = 0.0f;
#pragma unroll
            for (int m = 0; m < 24; ++m) {
                uint2 u = hr[m];
                f16x2 p0 = __builtin_bit_cast(f16x2, u.x);
                f16x2 p1 = __builtin_bit_cast(f16x2, u.y);
                a = fmaf((float)p0.x, fcw_s[4 * m + 0], a);
                a = fmaf((float)p0.y, fcw_s[4 * m + 1], a);
                a = fmaf((float)p1.x, fcw_s[4 * m + 2], a);
                a = fmaf((float)p1.y, fcw_s[4 * m + 3], a);
            }
            out[(t0 + tid) * BB + b] = a + fcb + xs[(t0 + tid) & (CH - 1)];
        }
    };

    for (int t = 0; t < TT; ++t) {
        if (t > 0 && (t & (NS - 1)) == 0) {   // flush BEFORE any xs refill
            flush(t - NS);
            __syncthreads();
        }
        if ((t & (CH - 1)) == 0) {            // covers t=0 (also init barrier)
            for (int i = tid; i < CH; i += TH) xs[i] = x[(t + i) * BB + b];
            __syncthreads();
        }

        // ---- gate dots: 4 gates x 6 fdot2 over h(t-1) slice ----
        const int pr = (t - 1) & (NS - 1);    // t=0 -> 511 (zeros)
        const uint2* hrow =
            (const uint2*)((const uint32_t*)(hist + pr * ROWP) + 6 * s);
        uint2 ua = hrow[0], ub = hrow[1], uc = hrow[2];
        f16x2 h2[6] = {__builtin_bit_cast(f16x2, ua.x), __builtin_bit_cast(f16x2, ua.y),
                       __builtin_bit_cast(f16x2, ub.x), __builtin_bit_cast(f16x2, ub.y),
                       __builtin_bit_cast(f16x2, uc.x), __builtin_bit_cast(f16x2, uc.y)};
        const float xv = xs[t & (CH - 1)];

        float acc[4];
#pragma unroll
        for (int g = 0; g < 4; ++g) {
            acc[g] = lead ? fmaf(xv, wih[g], bias[g]) : 0.0f;
#pragma unroll
            for (int m = 0; m < 6; ++m) acc[g] = FDOT2(W[g][m], h2[m], acc[g]);
        }

        // ---- reduce over the 8 slice lanes: VALU DPP, no DS pipe ----
#pragma unroll
        for (int g = 0; g < 4; ++g) {
            acc[g] = dpp_add<DPP_XOR1>(acc[g]);   // i ^= 1
            acc[g] = dpp_add<DPP_XOR2>(acc[g]);   // i ^= 2  (quad sums)
            acc[g] = dpp_add<DPP_HMIR>(acc[g]);   // 0<-7: other quad's sum
        }

        // ---- c/h update in-register on the lead lane; write h(t) ----
        if (lead) {
            const float iv = sigm(acc[0]);
            const float fv = sigm(acc[1]);
            const float gv = tanh_f(acc[2]);
            const float ov = sigm(acc[3]);
            c = fmaf(fv, c, iv * gv);
            const float h = ov * tanh_f(c);
            hist[(t & (NS - 1)) * ROWP + j] = (_Float16)h;
        }
        __syncthreads();   // h(t) visible; hist row t&511 overwrite safe
    }
    flush(TT - NS);        // last window (loop ended with a barrier)
}

extern "C" void kernel_launch(void* const* d_in, const int* in_sizes, int n_in,
                              void* d_out, int out_size, void* d_ws, size_t ws_size,
                              hipStream_t stream) {
    const float* x    = (const float*)d_in[0];
    const float* w_ih = (const float*)d_in[1];
    const float* w_hh = (const float*)d_in[2];
    const float* b_ih = (const float*)d_in[3];
    const float* b_hh = (const float*)d_in[4];
    const float* fc_w = (const float*)d_in[5];
    const float* fc_b = (const float*)d_in[6];
    float* out = (float*)d_out;

    lstm_kernel<<<dim3(BB), dim3(TH), 0, stream>>>(x, w_ih, w_hh, b_ih, b_hh,
                                                   fc_w, fc_b, out);
}